// Round 1
// 208.984 us; speedup vs baseline: 1.0088x; 1.0088x over previous
//
#include <hip/hip_runtime.h>
#include <stdint.h>

// MHA forward.  Inputs FP32, output FP32.  Compute: bf16 MFMA, fp32 accumulate.
// B=2,S=2048,D=1024,H=16,HD=64.
//
// hs=16 fast path:
//   x2b : x fp32 -> xb bf16 (aliased into A2sl region)
//   t1  : Wo -> WoT; Wq/Wk/Wv cols -> WT3sl
//   k2  : xb @ WT3sl^T -> Qsl (pre-scaled 0.125*log2e) / Ksl, VTsl  [global_load_lds]
//   k3  : attn v6 = v5 numerics/schedule (paired q-tiles -> 17 iters/block,
//         dbuf K/V + reg prefetch, no-max exp2 softmax, l via ones-MFMA,
//         truncated-bf16 P, stride-36 lsP) but 256-thr blocks x 2/CU:
//         each block owns a 64-row slice of the q-tile pair -> grid 2x (512),
//         two independent barrier domains per CU fill latency stalls.
//         XCD-chunk swizzle co-locates same-(b,h) blocks per XCD L2.
//   k4  : A2sl @ WoT^T + bo -> fp32 out  [global_load_lds]

typedef unsigned short u16;
typedef __attribute__((ext_vector_type(8))) short bf16x8;
typedef __attribute__((ext_vector_type(4))) float f32x4;

#define MFMA_BF16(a, b, c) __builtin_amdgcn_mfma_f32_16x16x32_bf16((a), (b), (c), 0, 0, 0)
#define QSCALE 0.18033688011112042f  // 0.125 * log2(e)

__device__ __forceinline__ u16 f2bf(float f) {  // RNE
  union { float f; unsigned int u; } x; x.f = f;
  unsigned int r = x.u + 0x7fffu + ((x.u >> 16) & 1u);
  return (u16)(r >> 16);
}
__device__ __forceinline__ bf16x8 pack8(float4 a, float4 b) {
  bf16x8 r;
  r[0] = (short)f2bf(a.x); r[1] = (short)f2bf(a.y);
  r[2] = (short)f2bf(a.z); r[3] = (short)f2bf(a.w);
  r[4] = (short)f2bf(b.x); r[5] = (short)f2bf(b.y);
  r[6] = (short)f2bf(b.z); r[7] = (short)f2bf(b.w);
  return r;
}
__device__ __forceinline__ void gload_lds16(const u16* g, u16* l) {
  __builtin_amdgcn_global_load_lds((__attribute__((address_space(1))) void*)g,
                                   (__attribute__((address_space(3))) void*)l, 16, 0, 0);
}

template <int CPR>
__device__ __forceinline__ int sw_off(int r, int c) {
  return (r * CPR + (c ^ (r & (CPR - 1)))) * 8;
}

__global__ __launch_bounds__(256) void x_to_bf16(const float* __restrict__ x,
                                                 u16* __restrict__ xb) {
  const size_t i = ((size_t)blockIdx.x * 256 + threadIdx.x) * 8;
  const float4 a = *(const float4*)&x[i];
  const float4 b = *(const float4*)&x[i + 4];
  *(bf16x8*)&xb[i] = pack8(a, b);
}

__global__ void transpose_cols(const float* __restrict__ W0, const float* __restrict__ W1,
                               const float* __restrict__ W2, u16* __restrict__ T,
                               int h0, int hsx64) {
  __shared__ u16 t[32][33];
  const int j0 = blockIdx.x * 32;
  const int g = j0 / hsx64;
  const float* W = (g == 0) ? W0 : (g == 1) ? W1 : W2;
  const int wc0 = h0 * 64 + (j0 % hsx64);
  const int k0 = blockIdx.y * 32;
  t[threadIdx.y][threadIdx.x] =
      f2bf(W[(size_t)(k0 + threadIdx.y) * 1024 + wc0 + threadIdx.x]);
  __syncthreads();
  T[(size_t)(j0 + threadIdx.y) * 1024 + k0 + threadIdx.x] = t[threadIdx.x][threadIdx.y];
}

// ---- k2/k4: C = A[M][K] @ BT[N][K]^T, 128x128 tile ----
template <int MODE, int AF32>
__global__ __launch_bounds__(256, 2) void gemm_bt(
    const void* __restrict__ Av, const u16* __restrict__ BT,
    void* __restrict__ C0v, u16* __restrict__ C1, u16* __restrict__ C2,
    const float* __restrict__ bias, int M, int N, int K, int hs, int h0) {
  __shared__ __align__(16) u16 lsA[128 * 32];
  __shared__ __align__(16) u16 lsB[128 * 32];
  const int tid = threadIdx.x, lane = tid & 63, wv = tid >> 6;
  const int quad = lane >> 4, l16 = lane & 15;
  const int m0 = blockIdx.y * 128, n0 = blockIdx.x * 128;
  const int wm = (wv >> 1) * 64, wn = (wv & 1) * 64;
  const int hs64 = hs * 64;
  f32x4 acc[4][4] = {};

  for (int k0 = 0; k0 < K; k0 += 32) {
    if constexpr (AF32) {
      bf16x8 va[2], vb[2];
#pragma unroll
      for (int c = 0; c < 2; ++c) {
        const int P = c * 256 + tid, r = P >> 2, cc = P & 3;
        const float* Af = (const float*)Av;
        const float4 a0 = *(const float4*)&Af[(size_t)(m0 + r) * K + k0 + cc * 8];
        const float4 a1 = *(const float4*)&Af[(size_t)(m0 + r) * K + k0 + cc * 8 + 4];
        va[c] = pack8(a0, a1);
        vb[c] = *(const bf16x8*)&BT[(size_t)(n0 + r) * K + k0 + cc * 8];
      }
      __syncthreads();
#pragma unroll
      for (int c = 0; c < 2; ++c) {
        const int P = c * 256 + tid, r = P >> 2, cc = P & 3;
        *(bf16x8*)&lsA[sw_off<4>(r, cc)] = va[c];
        *(bf16x8*)&lsB[sw_off<4>(r, cc)] = vb[c];
      }
      __syncthreads();
    } else {
      __syncthreads();
#pragma unroll
      for (int c = 0; c < 2; ++c) {
        const int P = c * 256 + tid, r = P >> 2;
        const int gcol = ((P & 3) ^ (r & 3)) * 8;
        gload_lds16((const u16*)Av + (size_t)(m0 + r) * K + k0 + gcol,
                    &lsA[(size_t)(c * 256 + wv * 64) * 8]);
        gload_lds16(BT + (size_t)(n0 + r) * K + k0 + gcol,
                    &lsB[(size_t)(c * 256 + wv * 64) * 8]);
      }
      __syncthreads();
    }
    bf16x8 af[4], bfr[4];
#pragma unroll
    for (int i = 0; i < 4; ++i) af[i] = *(const bf16x8*)&lsA[sw_off<4>(wm + i * 16 + l16, quad)];
#pragma unroll
    for (int j = 0; j < 4; ++j) bfr[j] = *(const bf16x8*)&lsB[sw_off<4>(wn + j * 16 + l16, quad)];
#pragma unroll
    for (int i = 0; i < 4; ++i)
#pragma unroll
      for (int j = 0; j < 4; ++j) acc[i][j] = MFMA_BF16(af[i], bfr[j], acc[i][j]);
  }

#pragma unroll
  for (int i = 0; i < 4; ++i)
#pragma unroll
    for (int j = 0; j < 4; ++j) {
      const int n = n0 + wn + j * 16 + l16;
      float bv = 0.f;
      if constexpr (MODE == 1) bv = bias[n];
#pragma unroll
      for (int r = 0; r < 4; ++r) {
        const int m = m0 + wm + i * 16 + quad * 4 + r;
        if constexpr (MODE == 3) {
          const int b = m >> 11, s = m & 2047;
          if (n < hs64) {
            ((u16*)C0v)[((size_t)b * 2048 + s) * hs64 + n] = f2bf(acc[i][j][r] * QSCALE);
          } else if (n < 2 * hs64) {
            C1[((size_t)b * 2048 + s) * hs64 + (n - hs64)] = f2bf(acc[i][j][r]);
          } else {
            const int nn = n - 2 * hs64;
            C2[((size_t)(b * hs + (nn >> 6)) * 64 + (nn & 63)) * 2048 + s] =
                f2bf(acc[i][j][r]);
          }
        } else {
          const int b = (m >= hs * 128) ? 1 : 0;
          const int rp = m - b * hs * 128;
          ((float*)C0v)[(size_t)(b * 2048 + h0 * 128 + rp) * 1024 + n] =
              acc[i][j][r] + bv;
        }
      }
    }
}

// ---- k3: attn v6 ----
// Grid 1D (16 * 2*hs) blocks of 256 thr / 4 waves x 16 q-rows = 64-row slice.
// Block owns slice (bx&1) of paired q-tiles (bx>>1, 15-(bx>>1)): 17 k-iters
// for every block (proven balance).  2 blocks/CU (LDS 70KB x2 <= 160KB) give
// two independent barrier domains per CU -> VALU/MFMA/LDS phases of the two
// blocks interleave and fill the dependency-chain stalls (was 20% occupancy,
// all pipes <31% busy).  XCD-chunk swizzle: dispatch d -> xcd d%8; work
// (d%8)*cpx + d/8 gives each XCD a contiguous bh range (4 bh = 2MB K+V -> L2
// resident), so the duplicated K/V re-reads of the split stay off HBM.
// Numerics: no-max exp2 softmax (scores bounded), l via ones-MFMA,
// truncation-packed bf16 P, stride-36 lsP (0 conflicts).
__global__ __launch_bounds__(256, 2) void attn_fwd(
    const u16* __restrict__ Qsl, const u16* __restrict__ Ksl,
    const u16* __restrict__ VTsl, u16* __restrict__ A2sl, int hs) {
  __shared__ __align__(16) u16 lsK[2][128 * 64];  // 2x16KB [key][hd], CPR=8
  __shared__ __align__(16) u16 lsV[2][64 * 128];  // 2x16KB [hd][key], CPR=16
  __shared__ __align__(16) u16 lsP[4][16 * 36];   // per-wave P, stride 36 (0-conflict)
  const int tid = threadIdx.x, lane = tid & 63, wv = tid >> 6;
  const int quad = lane >> 4, l16 = lane & 15;

  // bijective XCD-chunk swizzle (gridDim.x % 8 == 0 guaranteed by launcher)
  const int cpx = gridDim.x >> 3;
  const int w = (blockIdx.x & 7) * cpx + (blockIdx.x >> 3);
  const int bh = w >> 4;           // 0 .. 2*hs-1
  const int bx = w & 15;           // 0 .. 15
  const int pairidx = bx >> 1, slice = bx & 1;

  const int b = (bh >= hs) ? 1 : 0, hh = bh - b * hs;
  const int hs64 = hs * 64;
  const int wm = wv * 16;
  const u16* Qb = Qsl + (size_t)b * 2048 * hs64;
  const u16* Kb = Ksl + (size_t)b * 2048 * hs64;
  const u16* Vb = VTsl + (size_t)(b * hs + hh) * 64 * 2048;
  u16* A2b = A2sl + (size_t)(b * hs + hh) * 2048 * 64;
  u16* lsPw = &lsP[wv][0];

  bf16x8 ones;
#pragma unroll
  for (int i = 0; i < 8; ++i) ones[i] = (short)0x3F80;  // bf16 1.0

  bf16x8 vk[4], vv[4], nk[4], nv[4];
#pragma unroll
  for (int c = 0; c < 4; ++c) { nk[c] = {}; nv[c] = {}; }

  for (int half = 0; half < 2; ++half) {
    const int qt = (half == 0) ? pairidx : 15 - pairidx;
    const int q0 = qt * 128 + slice * 64;  // this block's 64 q-rows

    bf16x8 qf[2];
#pragma unroll
    for (int ks = 0; ks < 2; ++ks)
      qf[ks] = *(const bf16x8*)&Qb[(size_t)(q0 + wm + l16) * hs64 + hh * 64 +
                                   ks * 32 + quad * 8];

    f32x4 acc_o[4] = {};
    f32x4 acc_l = {};

    // preload tile 0 (4x16B K chunks + 4x16B V chunks per thread)
#pragma unroll
    for (int c = 0; c < 4; ++c) {
      const int P = c * 256 + tid;
      vk[c] = *(const bf16x8*)&Kb[(size_t)(P >> 3) * hs64 + hh * 64 + (P & 7) * 8];
      vv[c] = *(const bf16x8*)&Vb[(size_t)(P >> 4) * 2048 + (P & 15) * 8];
    }

    for (int kt = 0; kt <= qt; ++kt) {
      const int k0 = kt * 128;
      const int buf = kt & 1;
#pragma unroll
      for (int c = 0; c < 4; ++c) {
        const int P = c * 256 + tid;
        *(bf16x8*)&lsK[buf][sw_off<8>(P >> 3, P & 7)] = vk[c];
        *(bf16x8*)&lsV[buf][sw_off<16>(P >> 4, P & 15)] = vv[c];
      }
      if (kt < qt) {  // prefetch tile kt+1 behind this iter's compute
        const int k1 = k0 + 128;
#pragma unroll
        for (int c = 0; c < 4; ++c) {
          const int P = c * 256 + tid;
          nk[c] = *(const bf16x8*)&Kb[(size_t)(k1 + (P >> 3)) * hs64 + hh * 64 + (P & 7) * 8];
          nv[c] = *(const bf16x8*)&Vb[(size_t)(P >> 4) * 2048 + k1 + (P & 15) * 8];
        }
      }
      __syncthreads();

      // S = Q K^T (exp2-domain scale folded into Q)
      f32x4 accs[8] = {};
#pragma unroll
      for (int ks = 0; ks < 2; ++ks)
#pragma unroll
        for (int nj = 0; nj < 8; ++nj) {
          const bf16x8 kf =
              *(const bf16x8*)&lsK[buf][sw_off<8>(nj * 16 + l16, ks * 4 + quad)];
          accs[nj] = MFMA_BF16(qf[ks], kf, accs[nj]);
        }

      // no-max softmax: p = exp2(s); only diagonal tile masks
      const bool diag = (kt == qt);
#pragma unroll
      for (int nj = 0; nj < 8; ++nj)
#pragma unroll
        for (int r = 0; r < 4; ++r) {
          float p = exp2f(accs[nj][r]);
          if (diag) {
            const int col = k0 + nj * 16 + l16;
            const int grow = q0 + wm + quad * 4 + r;
            p = (col > grow) ? 0.f : p;
          }
          accs[nj][r] = p;
        }

      // O += P V ; l += P 1  (P truncation-packed to bf16 once, reused)
#pragma unroll
      for (int ks2 = 0; ks2 < 4; ++ks2) {
#pragma unroll
        for (int jj = 0; jj < 2; ++jj)
#pragma unroll
          for (int r = 0; r < 4; ++r) {
            union { float f; unsigned int u; } t;
            t.f = accs[ks2 * 2 + jj][r];
            lsPw[(quad * 4 + r) * 36 + jj * 16 + l16] = (u16)(t.u >> 16);
          }
        const bf16x8 pf = *(const bf16x8*)&lsPw[l16 * 36 + quad * 8];
        acc_l = MFMA_BF16(pf, ones, acc_l);
#pragma unroll
        for (int njo = 0; njo < 4; ++njo) {
          const bf16x8 vf =
              *(const bf16x8*)&lsV[buf][sw_off<16>(njo * 16 + l16, ks2 * 4 + quad)];
          acc_o[njo] = MFMA_BF16(pf, vf, acc_o[njo]);
        }
      }

#pragma unroll
      for (int c = 0; c < 4; ++c) { vk[c] = nk[c]; vv[c] = nv[c]; }
    }

#pragma unroll
    for (int r = 0; r < 4; ++r) {
      const int q = q0 + wm + quad * 4 + r;
      const float inv = 1.0f / acc_l[r];  // diagonal key always unmasked
#pragma unroll
      for (int njo = 0; njo < 4; ++njo)
        A2b[(size_t)q * 64 + njo * 16 + l16] = f2bf(acc_o[njo][r] * inv);
    }
    __syncthreads();  // half 0's buffers fully consumed before half 1 restages
  }
}

// ---------------- launcher ----------------
extern "C" void kernel_launch(void* const* d_in, const int* in_sizes, int n_in,
                              void* d_out, int out_size, void* d_ws, size_t ws_size,
                              hipStream_t stream) {
  (void)in_sizes; (void)n_in; (void)out_size;
  const float* x  = (const float*)d_in[0];
  const float* Wq = (const float*)d_in[1];
  const float* Wk = (const float*)d_in[2];
  const float* Wv = (const float*)d_in[3];
  const float* Wo = (const float*)d_in[4];
  const float* bo = (const float*)d_in[5];
  float* out = (float*)d_out;
  char* ws = (char*)d_ws;
  const size_t MB = 1024 * 1024;
  const size_t KB = 1024;

  int hs = 2;
  if      (ws_size >= 2 * MB + 16 * 2432 * KB) hs = 16;
  else if (ws_size >= 2 * MB +  8 * 2432 * KB) hs = 8;
  else if (ws_size >= 2 * MB +  4 * 2432 * KB) hs = 4;

  u16* WoT   = (u16*)(ws);
  u16* Ksl   = (u16*)(ws + 2 * MB);
  u16* VTsl  = (u16*)(ws + 2 * MB + (size_t)hs *  512 * KB);
  u16* A2sl  = (u16*)(ws + 2 * MB + (size_t)hs * 1024 * KB);
  u16* WT3sl = (u16*)(ws + 2 * MB + (size_t)hs * 1536 * KB);
  u16* Qsl   = (u16*)(ws + 2 * MB + (size_t)hs * 1920 * KB);

  transpose_cols<<<dim3(32, 32), dim3(32, 32), 0, stream>>>(Wo, Wo, Wo, WoT, 0, 1024);
  if (hs == 16) {
    u16* xb = A2sl;  // aliases A2sl: consumed by k2, overwritten by k3
    x_to_bf16<<<2048, 256, 0, stream>>>(x, xb);
    transpose_cols<<<dim3(96, 32), dim3(32, 32), 0, stream>>>(Wq, Wk, Wv, WT3sl, 0, 1024);
    gemm_bt<3, 0><<<dim3(24, 32), 256, 0, stream>>>(
        (const void*)xb, WT3sl, (void*)Qsl, Ksl, VTsl, nullptr, 4096, 3072, 1024, 16, 0);
    attn_fwd<<<dim3(512), 256, 0, stream>>>(Qsl, Ksl, VTsl, A2sl, 16);
    gemm_bt<1, 0><<<dim3(8, 32), 256, 0, stream>>>(
        (const void*)A2sl, WoT, (void*)out, nullptr, nullptr, bo, 4096, 1024, 1024, 16, 0);
  } else {
    for (int h0 = 0; h0 < 16; h0 += hs) {
      transpose_cols<<<dim3(6 * hs, 32), dim3(32, 32), 0, stream>>>(Wq, Wk, Wv, WT3sl, h0, hs * 64);
      gemm_bt<3, 1><<<dim3((3 * hs) / 2, 32), 256, 0, stream>>>(
          (const void*)x, WT3sl, (void*)Qsl, Ksl, VTsl, nullptr, 4096, 3 * hs * 64, 1024, hs, h0);
      attn_fwd<<<dim3(16 * 2 * hs), 256, 0, stream>>>(Qsl, Ksl, VTsl, A2sl, hs);
      gemm_bt<1, 0><<<dim3(8, 2 * hs), 256, 0, stream>>>(
          (const void*)A2sl, WoT, (void*)out, nullptr, nullptr, bo, 2 * hs * 128, 1024, 1024, hs, h0);
    }
  }
}

// Round 2
// 196.668 us; speedup vs baseline: 1.0719x; 1.0626x over previous
//
#include <hip/hip_runtime.h>
#include <stdint.h>

// MHA forward.  Inputs FP32, output FP32.  Compute: bf16 MFMA, fp32 accumulate.
// B=2,S=2048,D=1024,H=16,HD=64.
//
// hs=16 fast path:
//   x2b : x fp32 -> xb bf16 (aliased into A2sl region)
//   t1  : Wo -> WoT; Wq/Wk/Wv cols -> WT3sl
//   k2  : xb @ WT3sl^T -> Qsl (pre-scaled 0.125*log2e) / Ksl, VTsl  [global_load_lds]
//   k3  : attn v7. DS-pipe reduction round (v6 was ~70% DS-pipe-bound, 714cyc/wave-iter):
//         (a) K/V staging via global_load_lds (pre-swizzled global source, linear LDS
//             dest) -> no ds_write staging, no staging VGPRs.
//         (b) swapped QK^T: S^T = mfma(K, Q) puts adjacent keys in adjacent acc regs
//             -> P packs to bf16 pairs in-reg, P roundtrip = 8 ds_write_b64 + 4
//             ds_read_b128 (was 32 ds_write_b16 + 4 reads).  PV becomes
//             O^T = mfma(V^T, P^T) with the SAME lsV fragment reads; l = mfma(ones,P).
//         Keeps v6's 256-thr/4-wave 64-row slices, paired q-tiles (17 iters), dbuf
//         K/V, XCD-chunk swizzle, no-max exp2 softmax.
//   k4  : A2sl @ WoT^T + bo -> fp32 out  [global_load_lds]

typedef unsigned short u16;
typedef __attribute__((ext_vector_type(8))) short bf16x8;
typedef __attribute__((ext_vector_type(4))) float f32x4;

#define MFMA_BF16(a, b, c) __builtin_amdgcn_mfma_f32_16x16x32_bf16((a), (b), (c), 0, 0, 0)
#define QSCALE 0.18033688011112042f  // 0.125 * log2(e)

__device__ __forceinline__ u16 f2bf(float f) {  // RNE
  union { float f; unsigned int u; } x; x.f = f;
  unsigned int r = x.u + 0x7fffu + ((x.u >> 16) & 1u);
  return (u16)(r >> 16);
}
__device__ __forceinline__ bf16x8 pack8(float4 a, float4 b) {
  bf16x8 r;
  r[0] = (short)f2bf(a.x); r[1] = (short)f2bf(a.y);
  r[2] = (short)f2bf(a.z); r[3] = (short)f2bf(a.w);
  r[4] = (short)f2bf(b.x); r[5] = (short)f2bf(b.y);
  r[6] = (short)f2bf(b.z); r[7] = (short)f2bf(b.w);
  return r;
}
__device__ __forceinline__ void gload_lds16(const u16* g, u16* l) {
  __builtin_amdgcn_global_load_lds((__attribute__((address_space(1))) void*)g,
                                   (__attribute__((address_space(3))) void*)l, 16, 0, 0);
}

template <int CPR>
__device__ __forceinline__ int sw_off(int r, int c) {
  return (r * CPR + (c ^ (r & (CPR - 1)))) * 8;
}

__global__ __launch_bounds__(256) void x_to_bf16(const float* __restrict__ x,
                                                 u16* __restrict__ xb) {
  const size_t i = ((size_t)blockIdx.x * 256 + threadIdx.x) * 8;
  const float4 a = *(const float4*)&x[i];
  const float4 b = *(const float4*)&x[i + 4];
  *(bf16x8*)&xb[i] = pack8(a, b);
}

__global__ void transpose_cols(const float* __restrict__ W0, const float* __restrict__ W1,
                               const float* __restrict__ W2, u16* __restrict__ T,
                               int h0, int hsx64) {
  __shared__ u16 t[32][33];
  const int j0 = blockIdx.x * 32;
  const int g = j0 / hsx64;
  const float* W = (g == 0) ? W0 : (g == 1) ? W1 : W2;
  const int wc0 = h0 * 64 + (j0 % hsx64);
  const int k0 = blockIdx.y * 32;
  t[threadIdx.y][threadIdx.x] =
      f2bf(W[(size_t)(k0 + threadIdx.y) * 1024 + wc0 + threadIdx.x]);
  __syncthreads();
  T[(size_t)(j0 + threadIdx.y) * 1024 + k0 + threadIdx.x] = t[threadIdx.x][threadIdx.y];
}

// ---- k2/k4: C = A[M][K] @ BT[N][K]^T, 128x128 tile ----
template <int MODE, int AF32>
__global__ __launch_bounds__(256, 2) void gemm_bt(
    const void* __restrict__ Av, const u16* __restrict__ BT,
    void* __restrict__ C0v, u16* __restrict__ C1, u16* __restrict__ C2,
    const float* __restrict__ bias, int M, int N, int K, int hs, int h0) {
  __shared__ __align__(16) u16 lsA[128 * 32];
  __shared__ __align__(16) u16 lsB[128 * 32];
  const int tid = threadIdx.x, lane = tid & 63, wv = tid >> 6;
  const int quad = lane >> 4, l16 = lane & 15;
  const int m0 = blockIdx.y * 128, n0 = blockIdx.x * 128;
  const int wm = (wv >> 1) * 64, wn = (wv & 1) * 64;
  const int hs64 = hs * 64;
  f32x4 acc[4][4] = {};

  for (int k0 = 0; k0 < K; k0 += 32) {
    if constexpr (AF32) {
      bf16x8 va[2], vb[2];
#pragma unroll
      for (int c = 0; c < 2; ++c) {
        const int P = c * 256 + tid, r = P >> 2, cc = P & 3;
        const float* Af = (const float*)Av;
        const float4 a0 = *(const float4*)&Af[(size_t)(m0 + r) * K + k0 + cc * 8];
        const float4 a1 = *(const float4*)&Af[(size_t)(m0 + r) * K + k0 + cc * 8 + 4];
        va[c] = pack8(a0, a1);
        vb[c] = *(const bf16x8*)&BT[(size_t)(n0 + r) * K + k0 + cc * 8];
      }
      __syncthreads();
#pragma unroll
      for (int c = 0; c < 2; ++c) {
        const int P = c * 256 + tid, r = P >> 2, cc = P & 3;
        *(bf16x8*)&lsA[sw_off<4>(r, cc)] = va[c];
        *(bf16x8*)&lsB[sw_off<4>(r, cc)] = vb[c];
      }
      __syncthreads();
    } else {
      __syncthreads();
#pragma unroll
      for (int c = 0; c < 2; ++c) {
        const int P = c * 256 + tid, r = P >> 2;
        const int gcol = ((P & 3) ^ (r & 3)) * 8;
        gload_lds16((const u16*)Av + (size_t)(m0 + r) * K + k0 + gcol,
                    &lsA[(size_t)(c * 256 + wv * 64) * 8]);
        gload_lds16(BT + (size_t)(n0 + r) * K + k0 + gcol,
                    &lsB[(size_t)(c * 256 + wv * 64) * 8]);
      }
      __syncthreads();
    }
    bf16x8 af[4], bfr[4];
#pragma unroll
    for (int i = 0; i < 4; ++i) af[i] = *(const bf16x8*)&lsA[sw_off<4>(wm + i * 16 + l16, quad)];
#pragma unroll
    for (int j = 0; j < 4; ++j) bfr[j] = *(const bf16x8*)&lsB[sw_off<4>(wn + j * 16 + l16, quad)];
#pragma unroll
    for (int i = 0; i < 4; ++i)
#pragma unroll
      for (int j = 0; j < 4; ++j) acc[i][j] = MFMA_BF16(af[i], bfr[j], acc[i][j]);
  }

#pragma unroll
  for (int i = 0; i < 4; ++i)
#pragma unroll
    for (int j = 0; j < 4; ++j) {
      const int n = n0 + wn + j * 16 + l16;
      float bv = 0.f;
      if constexpr (MODE == 1) bv = bias[n];
#pragma unroll
      for (int r = 0; r < 4; ++r) {
        const int m = m0 + wm + i * 16 + quad * 4 + r;
        if constexpr (MODE == 3) {
          const int b = m >> 11, s = m & 2047;
          if (n < hs64) {
            ((u16*)C0v)[((size_t)b * 2048 + s) * hs64 + n] = f2bf(acc[i][j][r] * QSCALE);
          } else if (n < 2 * hs64) {
            C1[((size_t)b * 2048 + s) * hs64 + (n - hs64)] = f2bf(acc[i][j][r]);
          } else {
            const int nn = n - 2 * hs64;
            C2[((size_t)(b * hs + (nn >> 6)) * 64 + (nn & 63)) * 2048 + s] =
                f2bf(acc[i][j][r]);
          }
        } else {
          const int b = (m >= hs * 128) ? 1 : 0;
          const int rp = m - b * hs * 128;
          ((float*)C0v)[(size_t)(b * 2048 + h0 * 128 + rp) * 1024 + n] =
              acc[i][j][r] + bv;
        }
      }
    }
}

// ---- k3: attn v7 ----
// 256 thr / 4 waves x 16 q-rows = 64-row slice of paired q-tiles (17 iters).
// Swapped QK^T: accs[nj] = mfma(K,Q) -> lane holds S^T[key=nj*16+quad*4+r][q=l16].
// P packs reg-adjacent keys into bf16 pairs -> one ds_write_b64 per nj into
// XOR-swizzled lsP[q][key]; PV reads it back as the B operand of
// O^T = mfma(V^T, P^T) (lsV reads unchanged).  l = mfma(ones, P).
// K/V staged by global_load_lds: LDS dest linear, global source pre-swizzled so
// the semantic layout matches sw_off<8>/sw_off<16> (same reader code as v6).
__global__ __launch_bounds__(256, 2) void attn_fwd(
    const u16* __restrict__ Qsl, const u16* __restrict__ Ksl,
    const u16* __restrict__ VTsl, u16* __restrict__ A2sl, int hs) {
  __shared__ __align__(16) u16 lsK[2][128 * 64];  // 2x16KB [key][hd], CPR=8
  __shared__ __align__(16) u16 lsV[2][64 * 128];  // 2x16KB [hd][key], CPR=16
  __shared__ __align__(16) u16 lsP[4][16 * 128];  // per-wave P^T [q][key], XOR-swz
  const int tid = threadIdx.x, lane = tid & 63, wv = tid >> 6;
  const int quad = lane >> 4, l16 = lane & 15;

  // bijective XCD-chunk swizzle (gridDim.x % 8 == 0 guaranteed by launcher)
  const int cpx = gridDim.x >> 3;
  const int w = (blockIdx.x & 7) * cpx + (blockIdx.x >> 3);
  const int bh = w >> 4;           // 0 .. 2*hs-1
  const int bx = w & 15;           // 0 .. 15
  const int pairidx = bx >> 1, slice = bx & 1;

  const int b = (bh >= hs) ? 1 : 0, hh = bh - b * hs;
  const int hs64 = hs * 64;
  const int wm = wv * 16;
  const u16* Qb = Qsl + (size_t)b * 2048 * hs64;
  const u16* Kb = Ksl + (size_t)b * 2048 * hs64;
  const u16* Vb = VTsl + (size_t)(b * hs + hh) * 64 * 2048;
  u16* A2b = A2sl + (size_t)(b * hs + hh) * 2048 * 64;
  u16* lsPw = &lsP[wv][0];

  bf16x8 ones;
#pragma unroll
  for (int i = 0; i < 8; ++i) ones[i] = (short)0x3F80;  // bf16 1.0

  for (int half = 0; half < 2; ++half) {
    const int qt = (half == 0) ? pairidx : 15 - pairidx;
    const int q0 = qt * 128 + slice * 64;  // this block's 64 q-rows

    bf16x8 qf[2];
#pragma unroll
    for (int ks = 0; ks < 2; ++ks)
      qf[ks] = *(const bf16x8*)&Qb[(size_t)(q0 + wm + l16) * hs64 + hh * 64 +
                                   ks * 32 + quad * 8];

    f32x4 acc_o[4] = {};
    f32x4 acc_l = {};

    __syncthreads();  // prev half's buffers fully consumed before tile-0 DMA
    // stage tile 0 -> buf 0 (async; drained by the kt=0 barrier)
#pragma unroll
    for (int c = 0; c < 4; ++c) {
      const int P = c * 256 + tid;
      const int rK = P >> 3, cK = (P & 7) ^ (rK & 7);
      gload_lds16(Kb + (size_t)rK * hs64 + hh * 64 + cK * 8,
                  &lsK[0][(c * 256 + wv * 64) * 8]);
      const int rV = P >> 4, cV = (P & 15) ^ (rV & 15);
      gload_lds16(Vb + (size_t)rV * 2048 + cV * 8,
                  &lsV[0][(c * 256 + wv * 64) * 8]);
    }

    for (int kt = 0; kt <= qt; ++kt) {
      const int k0 = kt * 128;
      const int buf = kt & 1;
      __syncthreads();  // compiler drains vmcnt -> tile kt landed; buf^1 free
      if (kt < qt) {    // DMA tile kt+1 into buf^1 behind this iter's compute
        const int k1 = k0 + 128;
        const int nb = buf ^ 1;
#pragma unroll
        for (int c = 0; c < 4; ++c) {
          const int P = c * 256 + tid;
          const int rK = P >> 3, cK = (P & 7) ^ (rK & 7);
          gload_lds16(Kb + (size_t)(k1 + rK) * hs64 + hh * 64 + cK * 8,
                      &lsK[nb][(c * 256 + wv * 64) * 8]);
          const int rV = P >> 4, cV = (P & 15) ^ (rV & 15);
          gload_lds16(Vb + (size_t)rV * 2048 + k1 + cV * 8,
                      &lsV[nb][(c * 256 + wv * 64) * 8]);
        }
      }

      // S^T = K Q^T (exp2-domain scale folded into Q)
      f32x4 accs[8] = {};
#pragma unroll
      for (int ks = 0; ks < 2; ++ks)
#pragma unroll
        for (int nj = 0; nj < 8; ++nj) {
          const bf16x8 kf =
              *(const bf16x8*)&lsK[buf][sw_off<8>(nj * 16 + l16, ks * 4 + quad)];
          accs[nj] = MFMA_BF16(kf, qf[ks], accs[nj]);
        }

      // no-max softmax: p = exp2(s); only diagonal tile masks.
      // Lane holds keys (k0+nj*16+quad*4+r) for q-col (q0+wm+l16).
      const bool diag = (kt == qt);
      const int grow = q0 + wm + l16;
#pragma unroll
      for (int nj = 0; nj < 8; ++nj) {
        const int keyb = k0 + nj * 16 + quad * 4;
#pragma unroll
        for (int r = 0; r < 4; ++r) {
          float p = exp2f(accs[nj][r]);
          if (diag) p = (keyb + r > grow) ? 0.f : p;
          accs[nj][r] = p;
        }
        // truncation-pack 4 reg-adjacent keys -> one b64 LDS write
        union { float f; unsigned int u; } t0, t1, t2, t3;
        t0.f = accs[nj][0]; t1.f = accs[nj][1];
        t2.f = accs[nj][2]; t3.f = accs[nj][3];
        uint2 wpk;
        wpk.x = (t0.u >> 16) | (t1.u & 0xFFFF0000u);
        wpk.y = (t2.u >> 16) | (t3.u & 0xFFFF0000u);
        const int idx = (l16 * 128 + nj * 16 + quad * 4) ^ ((l16 & 7) << 3);
        *(uint2*)&lsPw[idx] = wpk;
      }

      // O^T += V^T P^T ; l += 1 P  (per-wave lsP: same-wave lgkmcnt dep only)
#pragma unroll
      for (int ks2 = 0; ks2 < 4; ++ks2) {
        const int pidx = (l16 * 128 + ks2 * 32 + quad * 8) ^ ((l16 & 7) << 3);
        const bf16x8 pf = *(const bf16x8*)&lsPw[pidx];
        acc_l = MFMA_BF16(ones, pf, acc_l);
#pragma unroll
        for (int njo = 0; njo < 4; ++njo) {
          const bf16x8 vf =
              *(const bf16x8*)&lsV[buf][sw_off<16>(njo * 16 + l16, ks2 * 4 + quad)];
          acc_o[njo] = MFMA_BF16(vf, pf, acc_o[njo]);
        }
      }
    }

    // epilogue: lane holds O^T[d = njo*16+quad*4+r][q = l16]; one rcp per lane
    const float inv = 1.0f / acc_l[0];  // all 4 regs equal; diag key unmasked -> l>0
#pragma unroll
    for (int njo = 0; njo < 4; ++njo) {
      uint2 o;
      o.x = (unsigned)f2bf(acc_o[njo][0] * inv) |
            ((unsigned)f2bf(acc_o[njo][1] * inv) << 16);
      o.y = (unsigned)f2bf(acc_o[njo][2] * inv) |
            ((unsigned)f2bf(acc_o[njo][3] * inv) << 16);
      *(uint2*)&A2b[(size_t)(q0 + wm + l16) * 64 + njo * 16 + quad * 4] = o;
    }
  }
}

// ---------------- launcher ----------------
extern "C" void kernel_launch(void* const* d_in, const int* in_sizes, int n_in,
                              void* d_out, int out_size, void* d_ws, size_t ws_size,
                              hipStream_t stream) {
  (void)in_sizes; (void)n_in; (void)out_size;
  const float* x  = (const float*)d_in[0];
  const float* Wq = (const float*)d_in[1];
  const float* Wk = (const float*)d_in[2];
  const float* Wv = (const float*)d_in[3];
  const float* Wo = (const float*)d_in[4];
  const float* bo = (const float*)d_in[5];
  float* out = (float*)d_out;
  char* ws = (char*)d_ws;
  const size_t MB = 1024 * 1024;
  const size_t KB = 1024;

  int hs = 2;
  if      (ws_size >= 2 * MB + 16 * 2432 * KB) hs = 16;
  else if (ws_size >= 2 * MB +  8 * 2432 * KB) hs = 8;
  else if (ws_size >= 2 * MB +  4 * 2432 * KB) hs = 4;

  u16* WoT   = (u16*)(ws);
  u16* Ksl   = (u16*)(ws + 2 * MB);
  u16* VTsl  = (u16*)(ws + 2 * MB + (size_t)hs *  512 * KB);
  u16* A2sl  = (u16*)(ws + 2 * MB + (size_t)hs * 1024 * KB);
  u16* WT3sl = (u16*)(ws + 2 * MB + (size_t)hs * 1536 * KB);
  u16* Qsl   = (u16*)(ws + 2 * MB + (size_t)hs * 1920 * KB);

  transpose_cols<<<dim3(32, 32), dim3(32, 32), 0, stream>>>(Wo, Wo, Wo, WoT, 0, 1024);
  if (hs == 16) {
    u16* xb = A2sl;  // aliases A2sl: consumed by k2, overwritten by k3
    x_to_bf16<<<2048, 256, 0, stream>>>(x, xb);
    transpose_cols<<<dim3(96, 32), dim3(32, 32), 0, stream>>>(Wq, Wk, Wv, WT3sl, 0, 1024);
    gemm_bt<3, 0><<<dim3(24, 32), 256, 0, stream>>>(
        (const void*)xb, WT3sl, (void*)Qsl, Ksl, VTsl, nullptr, 4096, 3072, 1024, 16, 0);
    attn_fwd<<<dim3(512), 256, 0, stream>>>(Qsl, Ksl, VTsl, A2sl, 16);
    gemm_bt<1, 0><<<dim3(8, 32), 256, 0, stream>>>(
        (const void*)A2sl, WoT, (void*)out, nullptr, nullptr, bo, 4096, 1024, 1024, 16, 0);
  } else {
    for (int h0 = 0; h0 < 16; h0 += hs) {
      transpose_cols<<<dim3(6 * hs, 32), dim3(32, 32), 0, stream>>>(Wq, Wk, Wv, WT3sl, h0, hs * 64);
      gemm_bt<3, 1><<<dim3((3 * hs) / 2, 32), 256, 0, stream>>>(
          (const void*)x, WT3sl, (void*)Qsl, Ksl, VTsl, nullptr, 4096, 3 * hs * 64, 1024, hs, h0);
      attn_fwd<<<dim3(16 * 2 * hs), 256, 0, stream>>>(Qsl, Ksl, VTsl, A2sl, hs);
      gemm_bt<1, 0><<<dim3(8, 2 * hs), 256, 0, stream>>>(
          (const void*)A2sl, WoT, (void*)out, nullptr, nullptr, bo, 2 * hs * 128, 1024, 1024, hs, h0);
    }
  }
}